// Round 2
// baseline (654.146 us; speedup 1.0000x reference)
//
#include <hip/hip_runtime.h>
#include <cstdint>
#include <cstddef>

// ---------------------------------------------------------------------------
// y = x @ W^T + lb  [B=32768, C=2048], K=2048 ; GroupNorm(32 groups of 64) ;
// per-row min ; out[0,c,b,0] = mins[b] + final_bias[c].
//
// R2: GEMM upgraded to the 256x256 8-phase schedule (T2 swizzle + T3/T4
// counted-vmcnt pipeline + T5 setprio). 8 waves (2Mx4N), BK=64, 128 KiB
// double-buffered LDS, 1 block/CU. All ds_reads in phases 1-2; prefetch
// issues only in phases 3-4 (after the all-reads-done barrier -> 2-buffer
// scheme is race-free); vmcnt(8) at tile boundary (next tile's 8 loads are
// the older ones and hence complete; next-next tile's 8 stay in flight).
// ---------------------------------------------------------------------------

#define AS1C(p) ((const __attribute__((address_space(1))) void*)(p))
#define AS3(p)  ((__attribute__((address_space(3))) void*)(p))

typedef short  short8  __attribute__((ext_vector_type(8)));
typedef int    int4v   __attribute__((ext_vector_type(4)));
typedef float  f32x4   __attribute__((ext_vector_type(4)));
typedef unsigned short ushort8 __attribute__((ext_vector_type(8)));

static constexpr int BDIM = 32768;
static constexpr int KDIM = 2048;
static constexpr int CDIM = 2048;

// ----------------------------- helpers -------------------------------------

__device__ __forceinline__ unsigned short f2bf(float f) {
    unsigned u = __float_as_uint(f);
    u += 0x7FFFu + ((u >> 16) & 1u);   // RNE
    return (unsigned short)(u >> 16);
}

__device__ __forceinline__ unsigned enc_min(float f) {
    unsigned u = __float_as_uint(f);
    return (u & 0x80000000u) ? ~u : (u | 0x80000000u);  // monotone float->uint
}

__device__ __forceinline__ float dec_min(unsigned e) {
    unsigned u = (e & 0x80000000u) ? (e ^ 0x80000000u) : ~e;
    return __uint_as_float(u);
}

// ----------------------------- k1: convert ---------------------------------

__global__ void convert_kernel(const float* __restrict__ src,
                               unsigned short* __restrict__ dst, int n8) {
    int i = blockIdx.x * blockDim.x + threadIdx.x;
    if (i >= n8) return;
    const float4* s4 = (const float4*)src;
    float4 a = s4[2 * i];
    float4 b = s4[2 * i + 1];
    ushort8 o;
    o[0] = f2bf(a.x); o[1] = f2bf(a.y); o[2] = f2bf(a.z); o[3] = f2bf(a.w);
    o[4] = f2bf(b.x); o[5] = f2bf(b.y); o[6] = f2bf(b.z); o[7] = f2bf(b.w);
    ((ushort8*)dst)[i] = o;
}

// ------------------- k2: fused GEMM + GroupNorm + row-min -------------------
// 256x256 tile, BK=64, 8 waves (wr in 0..1 -> 128 rows, wc in 0..3 -> 64 cols
// = exactly one GroupNorm group per wave).

__global__ __launch_bounds__(512, 2) void gemm_gn_min(
    const unsigned short* __restrict__ Abf,   // x   [32768,2048] bf16
    const unsigned short* __restrict__ Wbf,   // W   [2048,2048]  bf16
    const float* __restrict__ lb,
    const float* __restrict__ gw,
    const float* __restrict__ gb,
    unsigned int* mins_enc)
{
    // buf d: A at d*65536 (256 rows x 128B), B at d*65536+32768
    __shared__ unsigned char lds[131072];

    const int tid  = threadIdx.x;
    const int wid  = tid >> 6;
    const int lane = tid & 63;
    const int bj   = blockIdx.x & 7;          // C/256 = 8
    const int bi   = blockIdx.x >> 3;         // B/256 = 128
    const int row0 = bi * 256, col0 = bj * 256;
    const int wr = wid >> 2, wc = wid & 3;

    const int lrow = lane & 15;   // fragment row/col within 16
    const int lq   = lane >> 4;   // 0..3
    const int lx   = lane & 7;    // read-side XOR (== r&7 of every frag row)

    // ---- staging addressing (per-lane global src, linear wave-uniform LDS
    // dest; physical chunk p of LDS row r holds logical chunk p^(r&7)).
    const int soff   = wid * 8 + (lane >> 3);        // row within 64-row slab
    const int schunk = (lane & 7) ^ (lane >> 3);     // inverse-swizzled chunk
    const unsigned short* aSrc = Abf + (size_t)(row0 + soff) * KDIM + schunk * 8;
    const unsigned short* bSrc = Wbf + (size_t)(col0 + soff) * KDIM + schunk * 8;

    auto stageA = [&](int d, int kt, int slab) {
        __builtin_amdgcn_global_load_lds(
            AS1C(aSrc + (size_t)slab * 64 * KDIM + kt * 64),
            AS3(&lds[d * 65536 + (slab * 64 + wid * 8) * 128]), 16, 0, 0);
    };
    auto stageB = [&](int d, int kt, int slab) {
        __builtin_amdgcn_global_load_lds(
            AS1C(bSrc + (size_t)slab * 64 * KDIM + kt * 64),
            AS3(&lds[d * 65536 + 32768 + (slab * 64 + wid * 8) * 128]), 16, 0, 0);
    };

    auto rdA = [&](int d, int r, int ch) -> int4v {
        return *(const int4v*)&lds[d * 65536 + r * 128 + ((ch) ^ lx) * 16];
    };
    auto rdB = [&](int d, int r, int ch) -> int4v {
        return *(const int4v*)&lds[d * 65536 + 32768 + r * 128 + ((ch) ^ lx) * 16];
    };

    f32x4 acc[8][4] = {};
    int4v a03[4][2], a47[4][2], bb[4][2];

    // ---- prologue: issue tiles 0 and 1, wait for tile 0 (8 newest in flight)
#pragma unroll
    for (int t = 0; t < 2; ++t) {
#pragma unroll
        for (int s = 0; s < 4; ++s) stageA(t, t, s);
#pragma unroll
        for (int s = 0; s < 4; ++s) stageB(t, t, s);
    }
    asm volatile("s_waitcnt vmcnt(8)" ::: "memory");
    __builtin_amdgcn_s_barrier();
    asm volatile("" ::: "memory");

    auto tile = [&](int cur, int kt) {
        // ---- phase 1: reads A m0-3, B n0-1 (12 x ds_read_b128)
#pragma unroll
        for (int m = 0; m < 4; ++m)
#pragma unroll
            for (int ks = 0; ks < 2; ++ks)
                a03[m][ks] = rdA(cur, wr * 128 + m * 16 + lrow, ks * 4 + lq);
#pragma unroll
        for (int n = 0; n < 2; ++n)
#pragma unroll
            for (int ks = 0; ks < 2; ++ks)
                bb[n][ks] = rdB(cur, wc * 64 + n * 16 + lrow, ks * 4 + lq);
        __builtin_amdgcn_s_barrier();
        asm volatile("s_waitcnt lgkmcnt(0)" ::: "memory");
        __builtin_amdgcn_sched_barrier(0);
        __builtin_amdgcn_s_setprio(1);
#pragma unroll
        for (int m = 0; m < 4; ++m)
#pragma unroll
            for (int n = 0; n < 2; ++n)
#pragma unroll
                for (int ks = 0; ks < 2; ++ks)
                    acc[m][n] = __builtin_amdgcn_mfma_f32_16x16x32_bf16(
                        __builtin_bit_cast(short8, a03[m][ks]),
                        __builtin_bit_cast(short8, bb[n][ks]),
                        acc[m][n], 0, 0, 0);
        __builtin_amdgcn_s_setprio(0);

        // ---- phase 2: reads A m4-7, B n2-3
#pragma unroll
        for (int m = 0; m < 4; ++m)
#pragma unroll
            for (int ks = 0; ks < 2; ++ks)
                a47[m][ks] = rdA(cur, wr * 128 + (m + 4) * 16 + lrow, ks * 4 + lq);
#pragma unroll
        for (int n = 2; n < 4; ++n)
#pragma unroll
            for (int ks = 0; ks < 2; ++ks)
                bb[n][ks] = rdB(cur, wc * 64 + n * 16 + lrow, ks * 4 + lq);
        __builtin_amdgcn_s_barrier();
        asm volatile("s_waitcnt lgkmcnt(0)" ::: "memory");
        __builtin_amdgcn_sched_barrier(0);
        __builtin_amdgcn_s_setprio(1);
#pragma unroll
        for (int m = 0; m < 4; ++m)
#pragma unroll
            for (int n = 2; n < 4; ++n)
#pragma unroll
                for (int ks = 0; ks < 2; ++ks)
                    acc[m][n] = __builtin_amdgcn_mfma_f32_16x16x32_bf16(
                        __builtin_bit_cast(short8, a03[m][ks]),
                        __builtin_bit_cast(short8, bb[n][ks]),
                        acc[m][n], 0, 0, 0);
        __builtin_amdgcn_s_setprio(0);
        __builtin_amdgcn_s_barrier();            // ALL waves' reads of buf[cur] done
        asm volatile("" ::: "memory");

        // ---- phase 3: issue A-halves of tile kt+2 into buf[cur] (now safe)
        if (kt + 2 < KDIM / 64) {
#pragma unroll
            for (int s = 0; s < 4; ++s) stageA(cur, kt + 2, s);
        }
        __builtin_amdgcn_s_setprio(1);
#pragma unroll
        for (int m = 0; m < 4; ++m)
#pragma unroll
            for (int n = 0; n < 2; ++n)
#pragma unroll
                for (int ks = 0; ks < 2; ++ks)
                    acc[m + 4][n] = __builtin_amdgcn_mfma_f32_16x16x32_bf16(
                        __builtin_bit_cast(short8, a47[m][ks]),
                        __builtin_bit_cast(short8, bb[n][ks]),
                        acc[m + 4][n], 0, 0, 0);
        __builtin_amdgcn_s_setprio(0);
        __builtin_amdgcn_s_barrier();            // pacing
        asm volatile("" ::: "memory");

        // ---- phase 4: issue B-halves of tile kt+2
        if (kt + 2 < KDIM / 64) {
#pragma unroll
            for (int s = 0; s < 4; ++s) stageB(cur, kt + 2, s);
        }
        __builtin_amdgcn_s_setprio(1);
#pragma unroll
        for (int m = 0; m < 4; ++m)
#pragma unroll
            for (int n = 2; n < 4; ++n)
#pragma unroll
                for (int ks = 0; ks < 2; ++ks)
                    acc[m + 4][n] = __builtin_amdgcn_mfma_f32_16x16x32_bf16(
                        __builtin_bit_cast(short8, a47[m][ks]),
                        __builtin_bit_cast(short8, bb[n][ks]),
                        acc[m + 4][n], 0, 0, 0);
        __builtin_amdgcn_s_setprio(0);
        // counted wait: tile kt+1 (older 8 loads) landed; kt+2's 8 may fly
        if (kt + 2 < KDIM / 64)
            asm volatile("s_waitcnt vmcnt(8)" ::: "memory");
        else
            asm volatile("s_waitcnt vmcnt(0)" ::: "memory");
        __builtin_amdgcn_s_barrier();            // tile boundary
        asm volatile("" ::: "memory");
    };

    for (int kt = 0; kt < KDIM / 64; kt += 2) {
        tile(0, kt);
        tile(1, kt + 1);
    }

    // ---- epilogue: +bias, groupnorm over this wave's 64-col group, row min
    float lbv[4], gwv[4], gbv[4];
    const int cbase = col0 + wc * 64 + lrow;
#pragma unroll
    for (int n = 0; n < 4; ++n) {
        int c = cbase + n * 16;
        lbv[n] = lb[c]; gwv[n] = gw[c]; gbv[n] = gb[c];
    }

#pragma unroll
    for (int m = 0; m < 8; ++m) {
#pragma unroll
        for (int i = 0; i < 4; ++i) {
            float v[4];
            float s1 = 0.f, s2 = 0.f;
#pragma unroll
            for (int n = 0; n < 4; ++n) {
                v[n] = acc[m][n][i] + lbv[n];
                s1 += v[n];
                s2 += v[n] * v[n];
            }
#pragma unroll
            for (int mask = 1; mask <= 8; mask <<= 1) {
                s1 += __shfl_xor(s1, mask, 64);
                s2 += __shfl_xor(s2, mask, 64);
            }
            float mean = s1 * (1.f / 64.f);
            float var  = s2 * (1.f / 64.f) - mean * mean;
            float rstd = rsqrtf(var + 1e-5f);
            float mn = 3.4e38f;
#pragma unroll
            for (int n = 0; n < 4; ++n) {
                float nv = (v[n] - mean) * rstd * gwv[n] + gbv[n];
                mn = fminf(mn, nv);
            }
#pragma unroll
            for (int mask = 1; mask <= 8; mask <<= 1)
                mn = fminf(mn, __shfl_xor(mn, mask, 64));
            if (lrow == 0) {
                int row = row0 + wr * 128 + m * 16 + lq * 4 + i;
                atomicMin(mins_enc + row, enc_min(mn));
            }
        }
    }
}

// --------------------------- k3: broadcast ----------------------------------

__global__ void finalize_kernel(const unsigned int* mins_enc,
                                const float* __restrict__ fb, float* out) {
    size_t t = (size_t)blockIdx.x * 256 + threadIdx.x;
    size_t flat = t * 4;                      // 4 consecutive b, same c
    int c = (int)(flat >> 15);
    if (c == 1088) return;                    // mins live here; fixup later
    int b = (int)(flat & 32767);
    uint4 e = *(const uint4*)(mins_enc + b);
    float bias = fb[c];
    float4 o;
    o.x = dec_min(e.x) + bias;
    o.y = dec_min(e.y) + bias;
    o.z = dec_min(e.z) + bias;
    o.w = dec_min(e.w) + bias;
    *(float4*)(out + flat) = o;
}

__global__ void fixup_kernel(const float* __restrict__ fb, float* out) {
    int b = blockIdx.x * 256 + threadIdx.x;
    size_t idx = (size_t)1088 * 32768 + b;
    unsigned e = ((const unsigned*)out)[idx];  // read own cell first
    out[idx] = dec_min(e) + fb[1088];
}

// ----------------------------- launcher -------------------------------------

extern "C" void kernel_launch(void* const* d_in, const int* in_sizes, int n_in,
                              void* d_out, int out_size, void* d_ws, size_t ws_size,
                              hipStream_t stream) {
    const float* x  = (const float*)d_in[0];
    const float* w  = (const float*)d_in[1];
    const float* lb = (const float*)d_in[2];
    const float* gw = (const float*)d_in[3];
    const float* gb = (const float*)d_in[4];
    const float* fb = (const float*)d_in[5];
    float* out = (float*)d_out;

    // scratch regions inside d_out (268 MB total):
    unsigned short* xb = (unsigned short*)d_out;                        // 128 MiB
    unsigned short* wb = (unsigned short*)((char*)d_out + 134217728);   //   8 MiB
    unsigned int* mins = (unsigned int*)((char*)d_out + (size_t)1088 * 32768 * 4);

    // k1: fp32 -> bf16
    {
        int n8 = (BDIM * KDIM) / 8;
        convert_kernel<<<(n8 + 255) / 256, 256, 0, stream>>>(x, xb, n8);
    }
    {
        int n8 = (CDIM * KDIM) / 8;
        convert_kernel<<<(n8 + 255) / 256, 256, 0, stream>>>(w, wb, n8);
    }

    // init encoded mins to 0xFFFFFFFF (>= every encoding)
    hipMemsetAsync((void*)mins, 0xFF, (size_t)BDIM * 4, stream);

    // k2: fused GEMM + GN + min  (256x256 tiles -> 128x8 = 1024 blocks)
    gemm_gn_min<<<dim3((BDIM / 256) * (CDIM / 256)), dim3(512), 0, stream>>>(
        xb, wb, lb, gw, gb, mins);

    // k3: broadcast (skips c==1088), then fixup c==1088
    finalize_kernel<<<(BDIM / 4) * CDIM / 256, 256, 0, stream>>>(mins, fb, out);
    fixup_kernel<<<BDIM / 256, 256, 0, stream>>>(fb, out);
}

// Round 3
// 406.475 us; speedup vs baseline: 1.6093x; 1.6093x over previous
//
#include <hip/hip_runtime.h>
#include <cstdint>
#include <cstddef>

// ---------------------------------------------------------------------------
// y = x @ W^T + lb  [B=32768, C=2048], K=2048 ; GroupNorm(32 groups of 64) ;
// per-row min ; out[0,c,b,0] = mins[b] + final_bias[c].
//
// R3: faithful m201-style 8-phase ring schedule. 256x256 tile, BK=64,
// 8 waves (2Mx4N), 128 KiB dbuf LDS. Per phase: {<=12 ds_read_b128 |
// stage ONE half-tile (2 global_load_lds/wave) | bar | lgkmcnt(0) |
// setprio(1) 16 MFMA setprio(0) | bar}. Region-liveness ring:
//   ph1: rd a03+b01, stage B-h0(kt+1)->other   ph2: rd a47, stage B-h1(kt+1)
//   ph3: rd b23, stage A-h0(kt+2)->same        ph4: stage A-h1(kt+2), vmcnt(4)
// vmcnt(4) at tile boundary keeps A(kt+2)'s 4 loads in flight (never 0).
// ---------------------------------------------------------------------------

#define AS1C(p) ((const __attribute__((address_space(1))) void*)(p))
#define AS3(p)  ((__attribute__((address_space(3))) void*)(p))

typedef short  short8  __attribute__((ext_vector_type(8)));
typedef int    int4v   __attribute__((ext_vector_type(4)));
typedef float  f32x4   __attribute__((ext_vector_type(4)));
typedef unsigned short ushort8 __attribute__((ext_vector_type(8)));

static constexpr int BDIM = 32768;
static constexpr int KDIM = 2048;
static constexpr int CDIM = 2048;

// ----------------------------- helpers -------------------------------------

__device__ __forceinline__ unsigned short f2bf(float f) {
    unsigned u = __float_as_uint(f);
    u += 0x7FFFu + ((u >> 16) & 1u);   // RNE
    return (unsigned short)(u >> 16);
}

__device__ __forceinline__ unsigned enc_min(float f) {
    unsigned u = __float_as_uint(f);
    return (u & 0x80000000u) ? ~u : (u | 0x80000000u);  // monotone float->uint
}

__device__ __forceinline__ float dec_min(unsigned e) {
    unsigned u = (e & 0x80000000u) ? (e ^ 0x80000000u) : ~e;
    return __uint_as_float(u);
}

// ----------------------------- k1: convert ---------------------------------

__global__ void convert_kernel(const float* __restrict__ src,
                               unsigned short* __restrict__ dst, int n8) {
    int i = blockIdx.x * blockDim.x + threadIdx.x;
    if (i >= n8) return;
    const float4* s4 = (const float4*)src;
    float4 a = s4[2 * i];
    float4 b = s4[2 * i + 1];
    ushort8 o;
    o[0] = f2bf(a.x); o[1] = f2bf(a.y); o[2] = f2bf(a.z); o[3] = f2bf(a.w);
    o[4] = f2bf(b.x); o[5] = f2bf(b.y); o[6] = f2bf(b.z); o[7] = f2bf(b.w);
    ((ushort8*)dst)[i] = o;
}

// ------------------- k2: fused GEMM + GroupNorm + row-min -------------------

__global__ __launch_bounds__(512, 2) void gemm_gn_min(
    const unsigned short* __restrict__ Abf,   // x [32768,2048] bf16
    const unsigned short* __restrict__ Wbf,   // W [2048,2048]  bf16
    const float* __restrict__ lb,
    const float* __restrict__ gw,
    const float* __restrict__ gb,
    unsigned int* mins_enc)
{
    // buf d: A at d*65536 (256 rows x 128B), B at d*65536+32768
    __shared__ unsigned char lds[131072];

    const int tid  = threadIdx.x;
    const int wid  = tid >> 6;
    const int lane = tid & 63;
    const int bj   = blockIdx.x & 7;          // C/256 = 8
    const int bi   = blockIdx.x >> 3;         // B/256 = 128
    const int row0 = bi * 256, col0 = bj * 256;
    const int wr = wid >> 2, wc = wid & 3;

    const int lrow = lane & 15;
    const int lq   = lane >> 4;
    const int lx   = lane & 7;    // read-side XOR (== r&7 of every frag row)

    // staging: per half-tile (128 rows), wave wid covers rows wid*16+s*8+(lane>>3),
    // s in {0,1}. LDS dest linear; global chunk pre-swizzled so physical chunk
    // p of LDS row r holds logical chunk p^(r&7); r&7 == lane>>3 here.
    const int schunk = (lane & 7) ^ (lane >> 3);
    const unsigned short* aSrc =
        Abf + (size_t)(row0 + wid * 16 + (lane >> 3)) * KDIM + schunk * 8;
    const unsigned short* bSrc =
        Wbf + (size_t)(col0 + wid * 16 + (lane >> 3)) * KDIM + schunk * 8;

    auto stageAh = [&](int d, int kt, int h) {
#pragma unroll
        for (int s = 0; s < 2; ++s)
            __builtin_amdgcn_global_load_lds(
                AS1C(aSrc + (size_t)(h * 128 + s * 8) * KDIM + kt * 64),
                AS3(&lds[d * 65536 + (h * 128 + wid * 16 + s * 8) * 128]),
                16, 0, 0);
    };
    auto stageBh = [&](int d, int kt, int h) {
#pragma unroll
        for (int s = 0; s < 2; ++s)
            __builtin_amdgcn_global_load_lds(
                AS1C(bSrc + (size_t)(h * 128 + s * 8) * KDIM + kt * 64),
                AS3(&lds[d * 65536 + 32768 + (h * 128 + wid * 16 + s * 8) * 128]),
                16, 0, 0);
    };

    auto rdA = [&](int d, int r, int ch) -> int4v {
        return *(const int4v*)&lds[d * 65536 + r * 128 + ((ch) ^ lx) * 16];
    };
    auto rdB = [&](int d, int r, int ch) -> int4v {
        return *(const int4v*)&lds[d * 65536 + 32768 + r * 128 + ((ch) ^ lx) * 16];
    };

    f32x4 acc[8][4] = {};
    int4v a03[4][2], a47[4][2], b01[2][2], b23[2][2];

#define PH_OPEN()                                              \
    __builtin_amdgcn_s_barrier();                              \
    asm volatile("s_waitcnt lgkmcnt(0)" ::: "memory");         \
    __builtin_amdgcn_sched_barrier(0);                         \
    __builtin_amdgcn_s_setprio(1);
#define PH_CLOSE()                                             \
    __builtin_amdgcn_s_setprio(0);                             \
    __builtin_amdgcn_s_barrier();                              \
    asm volatile("" ::: "memory");

    // ---- prologue: A(0), B(0), A(1); wait for A(0),B(0); A(1) 4 loads fly
    stageAh(0, 0, 0); stageAh(0, 0, 1);
    stageBh(0, 0, 0); stageBh(0, 0, 1);
    stageAh(1, 1, 0); stageAh(1, 1, 1);
    asm volatile("s_waitcnt vmcnt(4)" ::: "memory");
    __builtin_amdgcn_s_barrier();
    asm volatile("" ::: "memory");

    auto ktile = [&](int c, int kt, bool sb, bool sa) {
        const int o = c ^ 1;
        // ---------------- phase 1: rd a03 + b01, stage B-h0(kt+1)
#pragma unroll
        for (int m = 0; m < 4; ++m)
#pragma unroll
            for (int ks = 0; ks < 2; ++ks)
                a03[m][ks] = rdA(c, wr * 128 + m * 16 + lrow, ks * 4 + lq);
#pragma unroll
        for (int n = 0; n < 2; ++n)
#pragma unroll
            for (int ks = 0; ks < 2; ++ks)
                b01[n][ks] = rdB(c, wc * 64 + n * 16 + lrow, ks * 4 + lq);
        if (sb) stageBh(o, kt + 1, 0);
        PH_OPEN();
#pragma unroll
        for (int m = 0; m < 4; ++m)
#pragma unroll
            for (int n = 0; n < 2; ++n)
#pragma unroll
                for (int ks = 0; ks < 2; ++ks)
                    acc[m][n] = __builtin_amdgcn_mfma_f32_16x16x32_bf16(
                        __builtin_bit_cast(short8, a03[m][ks]),
                        __builtin_bit_cast(short8, b01[n][ks]),
                        acc[m][n], 0, 0, 0);
        PH_CLOSE();

        // ---------------- phase 2: rd a47, stage B-h1(kt+1)
#pragma unroll
        for (int m = 0; m < 4; ++m)
#pragma unroll
            for (int ks = 0; ks < 2; ++ks)
                a47[m][ks] = rdA(c, wr * 128 + (m + 4) * 16 + lrow, ks * 4 + lq);
        if (sb) stageBh(o, kt + 1, 1);
        PH_OPEN();
#pragma unroll
        for (int m = 0; m < 4; ++m)
#pragma unroll
            for (int n = 0; n < 2; ++n)
#pragma unroll
                for (int ks = 0; ks < 2; ++ks)
                    acc[m + 4][n] = __builtin_amdgcn_mfma_f32_16x16x32_bf16(
                        __builtin_bit_cast(short8, a47[m][ks]),
                        __builtin_bit_cast(short8, b01[n][ks]),
                        acc[m + 4][n], 0, 0, 0);
        PH_CLOSE();
        // A(kt) fully read chip-wide after this barrier.

        // ---------------- phase 3: rd b23, stage A-h0(kt+2) into SAME buf
#pragma unroll
        for (int n = 0; n < 2; ++n)
#pragma unroll
            for (int ks = 0; ks < 2; ++ks)
                b23[n][ks] = rdB(c, wc * 64 + (n + 2) * 16 + lrow, ks * 4 + lq);
        if (sa) stageAh(c, kt + 2, 0);
        PH_OPEN();
#pragma unroll
        for (int m = 0; m < 4; ++m)
#pragma unroll
            for (int n = 0; n < 2; ++n)
#pragma unroll
                for (int ks = 0; ks < 2; ++ks)
                    acc[m][n + 2] = __builtin_amdgcn_mfma_f32_16x16x32_bf16(
                        __builtin_bit_cast(short8, a03[m][ks]),
                        __builtin_bit_cast(short8, b23[n][ks]),
                        acc[m][n + 2], 0, 0, 0);
        PH_CLOSE();
        // B(kt) fully read chip-wide after this barrier.

        // ---------------- phase 4: stage A-h1(kt+2), counted vmcnt
        if (sa) stageAh(c, kt + 2, 1);
        PH_OPEN();
#pragma unroll
        for (int m = 0; m < 4; ++m)
#pragma unroll
            for (int n = 0; n < 2; ++n)
#pragma unroll
                for (int ks = 0; ks < 2; ++ks)
                    acc[m + 4][n + 2] = __builtin_amdgcn_mfma_f32_16x16x32_bf16(
                        __builtin_bit_cast(short8, a47[m][ks]),
                        __builtin_bit_cast(short8, b23[n][ks]),
                        acc[m + 4][n + 2], 0, 0, 0);
        __builtin_amdgcn_s_setprio(0);
        if (sa) asm volatile("s_waitcnt vmcnt(4)" ::: "memory");
        else    asm volatile("s_waitcnt vmcnt(0)" ::: "memory");
        __builtin_amdgcn_s_barrier();
        asm volatile("" ::: "memory");
    };

    for (int kt2 = 0; kt2 < 30; kt2 += 2) {
        ktile(0, kt2,     true, true);
        ktile(1, kt2 + 1, true, kt2 + 1 + 2 < KDIM / 64);
    }
    ktile(0, 30, true,  false);
    ktile(1, 31, false, false);

#undef PH_OPEN
#undef PH_CLOSE

    // ---- epilogue: +bias, groupnorm over this wave's 64-col group, row min
    float lbv[4], gwv[4], gbv[4];
    const int cbase = col0 + wc * 64 + lrow;
#pragma unroll
    for (int n = 0; n < 4; ++n) {
        int c = cbase + n * 16;
        lbv[n] = lb[c]; gwv[n] = gw[c]; gbv[n] = gb[c];
    }

#pragma unroll
    for (int m = 0; m < 8; ++m) {
#pragma unroll
        for (int i = 0; i < 4; ++i) {
            float v[4];
            float s1 = 0.f, s2 = 0.f;
#pragma unroll
            for (int n = 0; n < 4; ++n) {
                v[n] = acc[m][n][i] + lbv[n];
                s1 += v[n];
                s2 += v[n] * v[n];
            }
#pragma unroll
            for (int mask = 1; mask <= 8; mask <<= 1) {
                s1 += __shfl_xor(s1, mask, 64);
                s2 += __shfl_xor(s2, mask, 64);
            }
            float mean = s1 * (1.f / 64.f);
            float var  = s2 * (1.f / 64.f) - mean * mean;
            float rstd = rsqrtf(var + 1e-5f);
            float mn = 3.4e38f;
#pragma unroll
            for (int n = 0; n < 4; ++n) {
                float nv = (v[n] - mean) * rstd * gwv[n] + gbv[n];
                mn = fminf(mn, nv);
            }
#pragma unroll
            for (int mask = 1; mask <= 8; mask <<= 1)
                mn = fminf(mn, __shfl_xor(mn, mask, 64));
            if (lrow == 0) {
                int row = row0 + wr * 128 + m * 16 + lq * 4 + i;
                atomicMin(mins_enc + row, enc_min(mn));
            }
        }
    }
}

// --------------------------- k3: broadcast ----------------------------------

__global__ void finalize_kernel(const unsigned int* mins_enc,
                                const float* __restrict__ fb, float* out) {
    size_t t = (size_t)blockIdx.x * 256 + threadIdx.x;
    size_t flat = t * 4;                      // 4 consecutive b, same c
    int c = (int)(flat >> 15);
    if (c == 1088) return;                    // mins live here; fixup later
    int b = (int)(flat & 32767);
    uint4 e = *(const uint4*)(mins_enc + b);
    float bias = fb[c];
    float4 o;
    o.x = dec_min(e.x) + bias;
    o.y = dec_min(e.y) + bias;
    o.z = dec_min(e.z) + bias;
    o.w = dec_min(e.w) + bias;
    *(float4*)(out + flat) = o;
}

__global__ void fixup_kernel(const float* __restrict__ fb, float* out) {
    int b = blockIdx.x * 256 + threadIdx.x;
    size_t idx = (size_t)1088 * 32768 + b;
    unsigned e = ((const unsigned*)out)[idx];  // read own cell first
    out[idx] = dec_min(e) + fb[1088];
}

// ----------------------------- launcher -------------------------------------

extern "C" void kernel_launch(void* const* d_in, const int* in_sizes, int n_in,
                              void* d_out, int out_size, void* d_ws, size_t ws_size,
                              hipStream_t stream) {
    const float* x  = (const float*)d_in[0];
    const float* w  = (const float*)d_in[1];
    const float* lb = (const float*)d_in[2];
    const float* gw = (const float*)d_in[3];
    const float* gb = (const float*)d_in[4];
    const float* fb = (const float*)d_in[5];
    float* out = (float*)d_out;

    // scratch regions inside d_out (268 MB total):
    unsigned short* xb = (unsigned short*)d_out;                        // 128 MiB
    unsigned short* wb = (unsigned short*)((char*)d_out + 134217728);   //   8 MiB
    unsigned int* mins = (unsigned int*)((char*)d_out + (size_t)1088 * 32768 * 4);

    // k1: fp32 -> bf16
    {
        int n8 = (BDIM * KDIM) / 8;
        convert_kernel<<<(n8 + 255) / 256, 256, 0, stream>>>(x, xb, n8);
    }
    {
        int n8 = (CDIM * KDIM) / 8;
        convert_kernel<<<(n8 + 255) / 256, 256, 0, stream>>>(w, wb, n8);
    }

    // init encoded mins to 0xFFFFFFFF (>= every encoding)
    hipMemsetAsync((void*)mins, 0xFF, (size_t)BDIM * 4, stream);

    // k2: fused GEMM + GN + min  (256x256 tiles -> 128x8 = 1024 blocks)
    gemm_gn_min<<<dim3((BDIM / 256) * (CDIM / 256)), dim3(512), 0, stream>>>(
        xb, wb, lb, gw, gb, mins);

    // k3: broadcast (skips c==1088), then fixup c==1088
    finalize_kernel<<<(BDIM / 4) * CDIM / 256, 256, 0, stream>>>(mins, fb, out);
    fixup_kernel<<<BDIM / 256, 256, 0, stream>>>(fb, out);
}